// Round 1
// baseline (930.258 us; speedup 1.0000x reference)
//
#include <hip/hip_runtime.h>
#include <math.h>

typedef unsigned short u16;
typedef __bf16 bf16x8 __attribute__((ext_vector_type(8)));
typedef float f32x4 __attribute__((ext_vector_type(4)));

__device__ __forceinline__ u16 f2bf(float f) {
    unsigned u = __builtin_bit_cast(unsigned, f);
    u += 0x7FFFu + ((u >> 16) & 1u);
    return (u16)(u >> 16);
}
__device__ __forceinline__ float bf2f(u16 h) {
    return __builtin_bit_cast(float, ((unsigned)h) << 16);
}

// ---------------------------------------------------------------- converts
__global__ __launch_bounds__(256) void k_convert(const float* __restrict__ in,
                                                 u16* __restrict__ out, int n4) {
    int i = blockIdx.x * 256 + threadIdx.x;
    if (i >= n4) return;
    float4 v = ((const float4*)in)[i];
    union { u16 a[4]; unsigned long long q; } o;
    o.a[0] = f2bf(v.x); o.a[1] = f2bf(v.y); o.a[2] = f2bf(v.z); o.a[3] = f2bf(v.w);
    ((unsigned long long*)out)[i] = o.q;
}

// out[(c)*ldOut + colOff + r] = bf16(in[r*C + c]);  grid = (C/32, R/32)
__global__ __launch_bounds__(256) void k_transpose(const float* __restrict__ in, int R, int C,
                                                   u16* __restrict__ out, int ldOut, int colOff) {
    __shared__ float tile[32][33];
    int tr0 = blockIdx.y * 32;
    int tc0 = blockIdx.x * 32;
    int lr = threadIdx.x >> 5;   // 0..7
    int lc = threadIdx.x & 31;
#pragma unroll
    for (int i = 0; i < 4; i++) {
        int rr = lr + i * 8;
        tile[rr][lc] = in[(size_t)(tr0 + rr) * C + tc0 + lc];
    }
    __syncthreads();
#pragma unroll
    for (int i = 0; i < 4; i++) {
        int rr = lr + i * 8;
        out[(size_t)(tc0 + rr) * ldOut + colOff + tr0 + lc] = f2bf(tile[lc][rr]);
    }
}

// ---------------------------------------------------------------- features
// P[b, 0:16384]      = x0[u]*x0[v]
// P[b, 16384:20480]  = (1/sqrt3) * sum_m x1[u,m] x1[v,m]
// P[b, 20480:21504]  = (1/sqrt5) * sum_m x2[u,m] x2[v,m]
__global__ __launch_bounds__(256) void k_features(const float* __restrict__ t,
                                                  u16* __restrict__ P) {
    __shared__ float tr[480];
    int b = blockIdx.x, tid = threadIdx.x;
    for (int i = tid; i < 480; i += 256) tr[i] = t[(size_t)b * 480 + i];
    __syncthreads();
    u16* row = P + (size_t)b * 21504;
    const float s1 = 0.57735026918962576f;
    const float s2 = 0.44721359549995794f;
    for (int k = tid; k < 16384; k += 256) {
        int u = k >> 7, v = k & 127;
        row[k] = f2bf(tr[u] * tr[v]);
    }
    const float* x1 = tr + 128;
    for (int k = tid; k < 4096; k += 256) {
        int u = k >> 6, v = k & 63;
        float s = x1[u*3+0]*x1[v*3+0] + x1[u*3+1]*x1[v*3+1] + x1[u*3+2]*x1[v*3+2];
        row[16384 + k] = f2bf(s * s1);
    }
    const float* x2 = tr + 320;
    for (int k = tid; k < 1024; k += 256) {
        int u = k >> 5, v = k & 31;
        float s = 0.f;
#pragma unroll
        for (int m = 0; m < 5; m++) s += x2[u*5+m] * x2[v*5+m];
        row[20480 + k] = f2bf(s * s2);
    }
}

// ---------------------------------------------------------------- GEMM (NT)
// C[M,N] = scale * A[M,K] * B[N,K]^T + bias;  A,B bf16 (K contiguous), C fp32 or bf16
// BM=128, BN=64, BK=32, 128 threads (2 waves), wave w handles rows [w*64, w*64+64)
__global__ __launch_bounds__(128) void k_gemm(const u16* __restrict__ A, int ldA,
                                              const u16* __restrict__ B, int ldB,
                                              int K, float scale,
                                              const float* __restrict__ bias,
                                              float* __restrict__ Cf,
                                              u16* __restrict__ Cb, int ldC) {
    __shared__ u16 As[128][40];   // +8 pad: keeps 16B alignment, kills conflicts
    __shared__ u16 Bs[64][40];
    int tid = threadIdx.x;
    int wave = tid >> 6, lane = tid & 63;
    int m0 = blockIdx.y * 128, n0 = blockIdx.x * 64;

    f32x4 acc[4][4];
#pragma unroll
    for (int i = 0; i < 4; i++)
#pragma unroll
        for (int j = 0; j < 4; j++) acc[i][j] = (f32x4){0.f, 0.f, 0.f, 0.f};

    int kq = (lane >> 4) * 8;
    int ml = lane & 15;

    for (int k0 = 0; k0 < K; k0 += 32) {
#pragma unroll
        for (int r = 0; r < 4; r++) {             // A: 128 rows x 32 = 512 chunks of 8
            int c = tid + 128 * r;
            int row = c >> 2, ch = c & 3;
            uint4 v = *(const uint4*)(A + (size_t)(m0 + row) * ldA + k0 + ch * 8);
            *(uint4*)&As[row][ch * 8] = v;
        }
#pragma unroll
        for (int r = 0; r < 2; r++) {             // B: 64 rows x 32 = 256 chunks
            int c = tid + 128 * r;
            int row = c >> 2, ch = c & 3;
            uint4 v = *(const uint4*)(B + (size_t)(n0 + row) * ldB + k0 + ch * 8);
            *(uint4*)&Bs[row][ch * 8] = v;
        }
        __syncthreads();
        bf16x8 af[4], bfr[4];
#pragma unroll
        for (int i = 0; i < 4; i++)
            af[i] = *(const bf16x8*)&As[wave * 64 + i * 16 + ml][kq];
#pragma unroll
        for (int j = 0; j < 4; j++)
            bfr[j] = *(const bf16x8*)&Bs[j * 16 + ml][kq];
#pragma unroll
        for (int i = 0; i < 4; i++)
#pragma unroll
            for (int j = 0; j < 4; j++)
                acc[i][j] = __builtin_amdgcn_mfma_f32_16x16x32_bf16(af[i], bfr[j], acc[i][j], 0, 0, 0);
        __syncthreads();
    }

    int q = lane >> 4;      // C/D: col = lane&15, row = (lane>>4)*4 + reg
    int nl = lane & 15;
#pragma unroll
    for (int i = 0; i < 4; i++)
#pragma unroll
        for (int j = 0; j < 4; j++)
#pragma unroll
            for (int reg = 0; reg < 4; reg++) {
                int row = m0 + wave * 64 + i * 16 + q * 4 + reg;
                int col = n0 + j * 16 + nl;
                float v = acc[i][j][reg] * scale + (bias ? bias[col] : 0.0f);
                if (Cf) Cf[(size_t)row * ldC + col] = v;
                else    Cb[(size_t)row * ldC + col] = f2bf(v);
            }
}

// ---------------------------------------------------------------- rowwise LN
__device__ __forceinline__ float blockReduce(float v, float* red) {
#pragma unroll
    for (int off = 32; off > 0; off >>= 1) v += __shfl_down(v, off);
    __syncthreads();
    if ((threadIdx.x & 63) == 0) red[threadIdx.x >> 6] = v;
    __syncthreads();
    return red[0] + red[1] + red[2] + red[3];
}

__global__ __launch_bounds__(256) void k_ln_fwd(const float* __restrict__ X, int D,
    const float* __restrict__ g, const float* __restrict__ be,
    float* __restrict__ mu_out, float* __restrict__ r_out,
    u16* __restrict__ a_bf, float* __restrict__ a_f32) {
    __shared__ float red[4];
    int b = blockIdx.x, tid = threadIdx.x;
    const float* x = X + (size_t)b * D;
    int nd = D >> 8;
    float s = 0.f, s2 = 0.f;
    for (int r = 0; r < nd; r++) { float v = x[tid + (r << 8)]; s += v; s2 += v * v; }
    s = blockReduce(s, red);
    s2 = blockReduce(s2, red);
    float mu = s / D;
    float var = s2 / D - mu * mu;
    float rst = rsqrtf(var + 1e-6f);
    if (tid == 0) { mu_out[b] = mu; r_out[b] = rst; }
    for (int r = 0; r < nd; r++) {
        int i = tid + (r << 8);
        float xh = (x[i] - mu) * rst;
        float ln = xh * g[i] + be[i];
        float a = ln / (1.0f + expf(-ln));
        if (a_bf)  a_bf[(size_t)b * D + i] = f2bf(a);
        if (a_f32) a_f32[(size_t)b * D + i] = a;
    }
}

// d_x for y = silu(LN(x)*g+be), upstream grad = dup (or 1.0 if null)
__global__ __launch_bounds__(256) void k_ln_bwd(const float* __restrict__ dup,
    const float* __restrict__ X, const float* __restrict__ mu_in, const float* __restrict__ r_in,
    const float* __restrict__ g, const float* __restrict__ be,
    u16* __restrict__ out_bf, int D) {
    __shared__ float red[4];
    int b = blockIdx.x, tid = threadIdx.x;
    const float* x = X + (size_t)b * D;
    float mu = mu_in[b], rst = r_in[b];
    int nd = D >> 8;
    float w_[4], xh_[4];
    float sw = 0.f, swx = 0.f;
    for (int r = 0; r < nd; r++) {
        int i = tid + (r << 8);
        float xh = (x[i] - mu) * rst;
        float ln = xh * g[i] + be[i];
        float sg = 1.0f / (1.0f + expf(-ln));
        float dsilu = sg * (1.0f + ln * (1.0f - sg));
        float d = dup ? dup[(size_t)b * D + i] : 1.0f;
        float w = g[i] * dsilu * d;
        w_[r] = w; xh_[r] = xh;
        sw += w; swx += w * xh;
    }
    sw = blockReduce(sw, red);
    swx = blockReduce(swx, red);
    float invD = 1.0f / D;
    for (int r = 0; r < nd; r++) {
        int i = tid + (r << 8);
        float dx = rst * (w_[r] - sw * invD - xh_[r] * swx * invD);
        out_bf[(size_t)b * D + i] = f2bf(dx);
    }
}

// ---------------------------------------------------------------- contraction
// y[b,:] from G[b,:] (bf16, 21504) and t[b,:]; d_x = (G+G^T) x per segment
__global__ __launch_bounds__(512) void k_contract(const u16* __restrict__ G,
                                                  const float* __restrict__ t,
                                                  float* __restrict__ y) {
    __shared__ float tr[480];
    int b = blockIdx.x, tid = threadIdx.x;
    for (int i = tid; i < 480; i += 512) tr[i] = t[(size_t)b * 480 + i];
    __syncthreads();
    const u16* g = G + (size_t)b * 21504;
    const float s1 = 0.57735026918962576f;
    const float s2 = 0.44721359549995794f;
    if (tid < 128) {
        int u = tid;
        float acc = 0.f;
        for (int v = 0; v < 128; v++)
            acc += (bf2f(g[u * 128 + v]) + bf2f(g[v * 128 + u])) * tr[v];
        y[(size_t)b * 480 + u] = acc;
    } else if (tid < 320) {
        int j = tid - 128;
        int u = j / 3, m = j % 3;
        const u16* g1 = g + 16384;
        float acc = 0.f;
        for (int v = 0; v < 64; v++)
            acc += (bf2f(g1[u * 64 + v]) + bf2f(g1[v * 64 + u])) * tr[128 + v * 3 + m];
        y[(size_t)b * 480 + 128 + j] = acc * s1;
    } else if (tid < 480) {
        int j = tid - 320;
        int u = j / 5, m = j % 5;
        const u16* g2 = g + 20480;
        float acc = 0.f;
        for (int v = 0; v < 32; v++)
            acc += (bf2f(g2[u * 32 + v]) + bf2f(g2[v * 32 + u])) * tr[320 + v * 5 + m];
        y[(size_t)b * 480 + 320 + j] = acc * s2;
    }
}

// ---------------------------------------------------------------- launch
extern "C" void kernel_launch(void* const* d_in, const int* in_sizes, int n_in,
                              void* d_out, int out_size, void* d_ws, size_t ws_size,
                              hipStream_t stream) {
    const float* t   = (const float*)d_in[0];
    const float* w0  = (const float*)d_in[1];
    const float* w1  = (const float*)d_in[2];
    const float* w2  = (const float*)d_in[3];
    const float* W1  = (const float*)d_in[4];
    const float* b1  = (const float*)d_in[5];
    const float* g1  = (const float*)d_in[6];
    const float* be1 = (const float*)d_in[7];
    const float* W2  = (const float*)d_in[8];
    const float* b2  = (const float*)d_in[9];
    const float* g2  = (const float*)d_in[10];
    const float* be2 = (const float*)d_in[11];

    float* xout = (float*)d_out;                    // 2048*256
    float* yout = xout + (size_t)2048 * 256;        // 2048*480

    char* ws = (char*)d_ws;
    size_t off = 0;
    auto alloc = [&](size_t bytes) -> void* {
        void* p = ws + off;
        off += (bytes + 255) & ~(size_t)255;
        return p;
    };
    u16*   PG    = (u16*)alloc((size_t)2048 * 21504 * 2);  // P, later G (aliased)
    u16*   Wtb   = (u16*)alloc((size_t)1024 * 21504 * 2);  // W^T bf16; later Wb (aliased)
    u16*   W1b   = (u16*)alloc((size_t)1024 * 1024 * 2);
    u16*   W1tb  = (u16*)alloc((size_t)1024 * 1024 * 2);
    u16*   W2b   = (u16*)alloc((size_t)1024 * 256 * 2);
    u16*   W2tb  = (u16*)alloc((size_t)256 * 1024 * 2);
    u16*   h_bf  = (u16*)alloc((size_t)2048 * 1024 * 2);
    float* h1pre = (float*)alloc((size_t)2048 * 1024 * 4);
    float* mu1   = (float*)alloc(2048 * 4);
    float* r1    = (float*)alloc(2048 * 4);
    u16*   a1_bf = (u16*)alloc((size_t)2048 * 1024 * 2);
    float* h2pre = (float*)alloc((size_t)2048 * 256 * 4);
    float* mu2   = (float*)alloc(2048 * 4);
    float* r2    = (float*)alloc(2048 * 4);
    u16*   dh2b  = (u16*)alloc((size_t)2048 * 256 * 2);
    float* d_a1  = (float*)alloc((size_t)2048 * 1024 * 4);
    u16*   dh1b  = (u16*)alloc((size_t)2048 * 1024 * 2);
    u16*   de_bf = (u16*)alloc((size_t)2048 * 1024 * 2);
    (void)ws_size; (void)in_sizes; (void)n_in; (void)out_size;

    const float sF = 1.0f / sqrtf(21504.0f);

    // weights: transposed bf16 (for forward-direction GEMMs) + small straight converts
    k_transpose<<<dim3(32, 512), 256, 0, stream>>>(w0, 16384, 1024, Wtb, 21504, 0);
    k_transpose<<<dim3(32, 128), 256, 0, stream>>>(w1, 4096, 1024, Wtb, 21504, 16384);
    k_transpose<<<dim3(32, 32),  256, 0, stream>>>(w2, 1024, 1024, Wtb, 21504, 20480);
    k_transpose<<<dim3(32, 32),  256, 0, stream>>>(W1, 1024, 1024, W1tb, 1024, 0);
    k_transpose<<<dim3(8, 32),   256, 0, stream>>>(W2, 1024, 256, W2tb, 1024, 0);
    k_convert<<<1024 * 1024 / 1024, 256, 0, stream>>>(W1, W1b, 1024 * 1024 / 4);
    k_convert<<<1024 * 256 / 1024, 256, 0, stream>>>(W2, W2b, 1024 * 256 / 4);

    // features -> P
    k_features<<<2048, 256, 0, stream>>>(t, PG);

    // h = sF * P @ W^T  (bf16 out)
    k_gemm<<<dim3(16, 16), 128, 0, stream>>>(PG, 21504, Wtb, 21504, 21504, sF, nullptr,
                                             nullptr, h_bf, 1024);

    // Wtb now dead -> overwrite with straight-layout Wb (for the backward GEMM)
    u16* Wb = Wtb;
    k_convert<<<16384 * 1024 / 1024, 256, 0, stream>>>(w0, Wb, 16384 * 1024 / 4);
    k_convert<<<4096 * 1024 / 1024, 256, 0, stream>>>(w1, Wb + (size_t)16384 * 1024, 4096 * 1024 / 4);
    k_convert<<<1024 * 1024 / 1024, 256, 0, stream>>>(w2, Wb + (size_t)20480 * 1024, 1024 * 1024 / 4);

    // MLP forward
    k_gemm<<<dim3(16, 16), 128, 0, stream>>>(h_bf, 1024, W1tb, 1024, 1024, 1.0f, b1,
                                             h1pre, nullptr, 1024);
    k_ln_fwd<<<2048, 256, 0, stream>>>(h1pre, 1024, g1, be1, mu1, r1, a1_bf, nullptr);
    k_gemm<<<dim3(4, 16), 128, 0, stream>>>(a1_bf, 1024, W2tb, 1024, 1024, 1.0f, b2,
                                            h2pre, nullptr, 256);
    k_ln_fwd<<<2048, 256, 0, stream>>>(h2pre, 256, g2, be2, mu2, r2, nullptr, xout);

    // backward
    k_ln_bwd<<<2048, 256, 0, stream>>>(nullptr, h2pre, mu2, r2, g2, be2, dh2b, 256);
    k_gemm<<<dim3(16, 16), 128, 0, stream>>>(dh2b, 256, W2b, 256, 256, 1.0f, nullptr,
                                             d_a1, nullptr, 1024);
    k_ln_bwd<<<2048, 256, 0, stream>>>(d_a1, h1pre, mu1, r1, g1, be1, dh1b, 1024);
    k_gemm<<<dim3(16, 16), 128, 0, stream>>>(dh1b, 1024, W1b, 1024, 1024, sF, nullptr,
                                             nullptr, de_bf, 1024);

    // G = de @ W (NT with straight-layout Wb), bf16 out, aliases P
    k_gemm<<<dim3(336, 16), 128, 0, stream>>>(de_bf, 1024, Wb, 1024, 1024, 1.0f, nullptr,
                                              nullptr, PG, 21504);

    // y = (G+G^T) x per segment
    k_contract<<<2048, 512, 0, stream>>>(PG, t, yout);
}

// Round 2
// 644.829 us; speedup vs baseline: 1.4426x; 1.4426x over previous
//
#include <hip/hip_runtime.h>
#include <math.h>

typedef unsigned short u16;
typedef __bf16 bf16x8 __attribute__((ext_vector_type(8)));
typedef float f32x4 __attribute__((ext_vector_type(4)));

__device__ __forceinline__ u16 f2bf(float f) {
    unsigned u = __builtin_bit_cast(unsigned, f);
    u += 0x7FFFu + ((u >> 16) & 1u);
    return (u16)(u >> 16);
}
__device__ __forceinline__ float bf2f(u16 h) {
    return __builtin_bit_cast(float, ((unsigned)h) << 16);
}

#define GLOAD_LDS16(g, l)                                                     \
    __builtin_amdgcn_global_load_lds(                                         \
        (const __attribute__((address_space(1))) void*)(g),                   \
        (__attribute__((address_space(3))) void*)(l), 16, 0, 0)

// ---------------------------------------------------------------- converts
__global__ __launch_bounds__(256) void k_convert(const float* __restrict__ in,
                                                 u16* __restrict__ out, int n4) {
    int i = blockIdx.x * 256 + threadIdx.x;
    if (i >= n4) return;
    float4 v = ((const float4*)in)[i];
    union { u16 a[4]; unsigned long long q; } o;
    o.a[0] = f2bf(v.x); o.a[1] = f2bf(v.y); o.a[2] = f2bf(v.z); o.a[3] = f2bf(v.w);
    ((unsigned long long*)out)[i] = o.q;
}

// out[(c)*ldOut + colOff + r] = bf16(in[r*C + c]);  grid = (C/32, R/32)
__global__ __launch_bounds__(256) void k_transpose(const float* __restrict__ in, int R, int C,
                                                   u16* __restrict__ out, int ldOut, int colOff) {
    __shared__ float tile[32][33];
    int tr0 = blockIdx.y * 32;
    int tc0 = blockIdx.x * 32;
    int lr = threadIdx.x >> 5;   // 0..7
    int lc = threadIdx.x & 31;
#pragma unroll
    for (int i = 0; i < 4; i++) {
        int rr = lr + i * 8;
        tile[rr][lc] = in[(size_t)(tr0 + rr) * C + tc0 + lc];
    }
    __syncthreads();
#pragma unroll
    for (int i = 0; i < 4; i++) {
        int rr = lr + i * 8;
        out[(size_t)(tc0 + rr) * ldOut + colOff + tr0 + lc] = f2bf(tile[lc][rr]);
    }
}

// ---------------------------------------------------------------- features
__global__ __launch_bounds__(256) void k_features(const float* __restrict__ t,
                                                  u16* __restrict__ P) {
    __shared__ float tr[480];
    int b = blockIdx.x, tid = threadIdx.x;
    for (int i = tid; i < 480; i += 256) tr[i] = t[(size_t)b * 480 + i];
    __syncthreads();
    u16* row = P + (size_t)b * 21504;
    const float s1 = 0.57735026918962576f;
    const float s2 = 0.44721359549995794f;
    for (int k = tid; k < 16384; k += 256) {
        int u = k >> 7, v = k & 127;
        row[k] = f2bf(tr[u] * tr[v]);
    }
    const float* x1 = tr + 128;
    for (int k = tid; k < 4096; k += 256) {
        int u = k >> 6, v = k & 63;
        float s = x1[u*3+0]*x1[v*3+0] + x1[u*3+1]*x1[v*3+1] + x1[u*3+2]*x1[v*3+2];
        row[16384 + k] = f2bf(s * s1);
    }
    const float* x2 = tr + 320;
    for (int k = tid; k < 1024; k += 256) {
        int u = k >> 5, v = k & 31;
        float s = 0.f;
#pragma unroll
        for (int m = 0; m < 5; m++) s += x2[u*5+m] * x2[v*5+m];
        row[20480 + k] = f2bf(s * s2);
    }
}

// ---------------------------------------------------------------- GEMM (NT, m97 structure)
// C[M,N] = scale*A[M,K]*B[N,K]^T + bias. 128x128x32 tile, 256 thr (2x2 waves),
// global_load_lds width-16 staging, unpadded LDS (required by load_lds layout).
// gridDim.z>1 => split-K: write fp32 partials to Cpart[z][M][ldC], no epilogue.
__global__ __launch_bounds__(256) void k_gemm2(const u16* __restrict__ A, int ldA,
                                               const u16* __restrict__ B, int ldB,
                                               int kLen, float scale,
                                               const float* __restrict__ bias,
                                               float* __restrict__ Cf,
                                               u16* __restrict__ Cb, int ldC,
                                               float* __restrict__ Cpart) {
    __shared__ u16 As[128 * 32];
    __shared__ u16 Bs[128 * 32];
    const int tid = threadIdx.x;
    const int wave = tid >> 6, lane = tid & 63;
    const int wm = wave >> 1, wn = wave & 1;
    const int m0 = blockIdx.y * 128, n0 = blockIdx.x * 128;
    const size_t kOff = (size_t)blockIdx.z * kLen;

    // staging: wave covers rows [wave*32, wave*32+32): 2 issues of 16 rows each.
    // lane L of an issue -> row base+L/4, col (L&3)*8 (16B); LDS dst = base + lane*16B.
    const u16* aG = A + (size_t)(m0 + wave * 32 + (lane >> 2)) * ldA + kOff + (lane & 3) * 8;
    const u16* bG = B + (size_t)(n0 + wave * 32 + (lane >> 2)) * ldB + kOff + (lane & 3) * 8;
    const size_t aStep16 = (size_t)16 * ldA;
    const size_t bStep16 = (size_t)16 * ldB;
    u16* aL0 = &As[(wave * 32) * 32];
    u16* aL1 = &As[(wave * 32 + 16) * 32];
    u16* bL0 = &Bs[(wave * 32) * 32];
    u16* bL1 = &Bs[(wave * 32 + 16) * 32];

    f32x4 acc[4][4];
#pragma unroll
    for (int i = 0; i < 4; i++)
#pragma unroll
        for (int j = 0; j < 4; j++) acc[i][j] = (f32x4){0.f, 0.f, 0.f, 0.f};

    const int ml = lane & 15, kq = (lane >> 4) * 8;
    const u16* aRd = &As[(wm * 64 + ml) * 32 + kq];
    const u16* bRd = &Bs[(wn * 64 + ml) * 32 + kq];

    for (int k = 0; k < kLen; k += 32) {
        GLOAD_LDS16(aG, aL0);
        GLOAD_LDS16(aG + aStep16, aL1);
        GLOAD_LDS16(bG, bL0);
        GLOAD_LDS16(bG + bStep16, bL1);
        aG += 32; bG += 32;
        __syncthreads();
        bf16x8 af[4], bfr[4];
#pragma unroll
        for (int i = 0; i < 4; i++) af[i]  = *(const bf16x8*)(aRd + i * 16 * 32);
#pragma unroll
        for (int j = 0; j < 4; j++) bfr[j] = *(const bf16x8*)(bRd + j * 16 * 32);
#pragma unroll
        for (int i = 0; i < 4; i++)
#pragma unroll
            for (int j = 0; j < 4; j++)
                acc[i][j] = __builtin_amdgcn_mfma_f32_16x16x32_bf16(af[i], bfr[j], acc[i][j], 0, 0, 0);
        __syncthreads();
    }

    const int q = lane >> 4, nl = lane & 15;   // C/D: col=lane&15, row=(lane>>4)*4+reg
    if (gridDim.z > 1) {
        float* outP = Cpart + (size_t)blockIdx.z * ((size_t)gridDim.y * 128) * ldC;
#pragma unroll
        for (int i = 0; i < 4; i++)
#pragma unroll
            for (int j = 0; j < 4; j++)
#pragma unroll
                for (int reg = 0; reg < 4; reg++) {
                    int row = m0 + wm * 64 + i * 16 + q * 4 + reg;
                    int col = n0 + wn * 64 + j * 16 + nl;
                    outP[(size_t)row * ldC + col] = acc[i][j][reg];
                }
    } else {
#pragma unroll
        for (int i = 0; i < 4; i++)
#pragma unroll
            for (int j = 0; j < 4; j++)
#pragma unroll
                for (int reg = 0; reg < 4; reg++) {
                    int row = m0 + wm * 64 + i * 16 + q * 4 + reg;
                    int col = n0 + wn * 64 + j * 16 + nl;
                    float v = acc[i][j][reg] * scale + (bias ? bias[col] : 0.0f);
                    if (Cf) Cf[(size_t)row * ldC + col] = v;
                    else    Cb[(size_t)row * ldC + col] = f2bf(v);
                }
    }
}

// sum split-K partials + epilogue
__global__ __launch_bounds__(256) void k_reduce(const float* __restrict__ part, size_t stride,
                                                int SK, int total, int N, float scale,
                                                const float* __restrict__ bias,
                                                float* __restrict__ outF, u16* __restrict__ outB) {
    int i = blockIdx.x * 256 + threadIdx.x;
    if (i >= total) return;
    float s = 0.f;
    for (int z = 0; z < SK; z++) s += part[(size_t)z * stride + i];
    float v = s * scale + (bias ? bias[i % N] : 0.0f);
    if (outF) outF[i] = v;
    else      outB[i] = f2bf(v);
}

// ---------------------------------------------------------------- rowwise LN
__device__ __forceinline__ float blockReduce(float v, float* red) {
#pragma unroll
    for (int off = 32; off > 0; off >>= 1) v += __shfl_down(v, off);
    __syncthreads();
    if ((threadIdx.x & 63) == 0) red[threadIdx.x >> 6] = v;
    __syncthreads();
    return red[0] + red[1] + red[2] + red[3];
}

__global__ __launch_bounds__(256) void k_ln_fwd(const float* __restrict__ X, int D,
    const float* __restrict__ g, const float* __restrict__ be,
    float* __restrict__ mu_out, float* __restrict__ r_out,
    u16* __restrict__ a_bf, float* __restrict__ a_f32) {
    __shared__ float red[4];
    int b = blockIdx.x, tid = threadIdx.x;
    const float* x = X + (size_t)b * D;
    int nd = D >> 8;
    float s = 0.f, s2 = 0.f;
    for (int r = 0; r < nd; r++) { float v = x[tid + (r << 8)]; s += v; s2 += v * v; }
    s = blockReduce(s, red);
    s2 = blockReduce(s2, red);
    float mu = s / D;
    float var = s2 / D - mu * mu;
    float rst = rsqrtf(var + 1e-6f);
    if (tid == 0) { mu_out[b] = mu; r_out[b] = rst; }
    for (int r = 0; r < nd; r++) {
        int i = tid + (r << 8);
        float xh = (x[i] - mu) * rst;
        float ln = xh * g[i] + be[i];
        float a = ln / (1.0f + expf(-ln));
        if (a_bf)  a_bf[(size_t)b * D + i] = f2bf(a);
        if (a_f32) a_f32[(size_t)b * D + i] = a;
    }
}

__global__ __launch_bounds__(256) void k_ln_bwd(const float* __restrict__ dup,
    const float* __restrict__ X, const float* __restrict__ mu_in, const float* __restrict__ r_in,
    const float* __restrict__ g, const float* __restrict__ be,
    u16* __restrict__ out_bf, int D) {
    __shared__ float red[4];
    int b = blockIdx.x, tid = threadIdx.x;
    const float* x = X + (size_t)b * D;
    float mu = mu_in[b], rst = r_in[b];
    int nd = D >> 8;
    float w_[4], xh_[4];
    float sw = 0.f, swx = 0.f;
    for (int r = 0; r < nd; r++) {
        int i = tid + (r << 8);
        float xh = (x[i] - mu) * rst;
        float ln = xh * g[i] + be[i];
        float sg = 1.0f / (1.0f + expf(-ln));
        float dsilu = sg * (1.0f + ln * (1.0f - sg));
        float d = dup ? dup[(size_t)b * D + i] : 1.0f;
        float w = g[i] * dsilu * d;
        w_[r] = w; xh_[r] = xh;
        sw += w; swx += w * xh;
    }
    sw = blockReduce(sw, red);
    swx = blockReduce(swx, red);
    float invD = 1.0f / D;
    for (int r = 0; r < nd; r++) {
        int i = tid + (r << 8);
        float dx = rst * (w_[r] - sw * invD - xh_[r] * swx * invD);
        out_bf[(size_t)b * D + i] = f2bf(dx);
    }
}

// ---------------------------------------------------------------- contraction
__global__ __launch_bounds__(512) void k_contract(const u16* __restrict__ G,
                                                  const float* __restrict__ t,
                                                  float* __restrict__ y) {
    __shared__ float tr[480];
    int b = blockIdx.x, tid = threadIdx.x;
    for (int i = tid; i < 480; i += 512) tr[i] = t[(size_t)b * 480 + i];
    __syncthreads();
    const u16* g = G + (size_t)b * 21504;
    const float s1 = 0.57735026918962576f;
    const float s2 = 0.44721359549995794f;
    if (tid < 128) {
        int u = tid;
        float acc = 0.f;
        for (int v = 0; v < 128; v++)
            acc += (bf2f(g[u * 128 + v]) + bf2f(g[v * 128 + u])) * tr[v];
        y[(size_t)b * 480 + u] = acc;
    } else if (tid < 320) {
        int j = tid - 128;
        int u = j / 3, m = j % 3;
        const u16* g1 = g + 16384;
        float acc = 0.f;
        for (int v = 0; v < 64; v++)
            acc += (bf2f(g1[u * 64 + v]) + bf2f(g1[v * 64 + u])) * tr[128 + v * 3 + m];
        y[(size_t)b * 480 + 128 + j] = acc * s1;
    } else if (tid < 480) {
        int j = tid - 320;
        int u = j / 5, m = j % 5;
        const u16* g2 = g + 20480;
        float acc = 0.f;
        for (int v = 0; v < 32; v++)
            acc += (bf2f(g2[u * 32 + v]) + bf2f(g2[v * 32 + u])) * tr[320 + v * 5 + m];
        y[(size_t)b * 480 + 320 + j] = acc * s2;
    }
}

// ---------------------------------------------------------------- launch
extern "C" void kernel_launch(void* const* d_in, const int* in_sizes, int n_in,
                              void* d_out, int out_size, void* d_ws, size_t ws_size,
                              hipStream_t stream) {
    const float* t   = (const float*)d_in[0];
    const float* w0  = (const float*)d_in[1];
    const float* w1  = (const float*)d_in[2];
    const float* w2  = (const float*)d_in[3];
    const float* W1  = (const float*)d_in[4];
    const float* b1  = (const float*)d_in[5];
    const float* g1  = (const float*)d_in[6];
    const float* be1 = (const float*)d_in[7];
    const float* W2  = (const float*)d_in[8];
    const float* b2  = (const float*)d_in[9];
    const float* g2  = (const float*)d_in[10];
    const float* be2 = (const float*)d_in[11];

    float* xout = (float*)d_out;                    // 2048*256
    float* yout = xout + (size_t)2048 * 256;        // 2048*480

    char* ws = (char*)d_ws;
    size_t off = 0;
    auto alloc = [&](size_t bytes) -> void* {
        void* p = ws + off;
        off += (bytes + 255) & ~(size_t)255;
        return p;
    };
    u16*   PG    = (u16*)alloc((size_t)2048 * 21504 * 2);  // P, later G (aliased)
    u16*   Wtb   = (u16*)alloc((size_t)1024 * 21504 * 2);  // W^T bf16; later Wb (aliased)
    u16*   W1b   = (u16*)alloc((size_t)1024 * 1024 * 2);
    u16*   W1tb  = (u16*)alloc((size_t)1024 * 1024 * 2);
    u16*   W2b   = (u16*)alloc((size_t)1024 * 256 * 2);
    u16*   W2tb  = (u16*)alloc((size_t)256 * 1024 * 2);
    u16*   h_bf  = (u16*)alloc((size_t)2048 * 1024 * 2);
    float* h1pre = (float*)alloc((size_t)2048 * 1024 * 4);
    float* mu1   = (float*)alloc(2048 * 4);
    float* r1    = (float*)alloc(2048 * 4);
    u16*   a1_bf = (u16*)alloc((size_t)2048 * 1024 * 2);
    float* h2pre = (float*)alloc((size_t)2048 * 256 * 4);
    float* mu2   = (float*)alloc(2048 * 4);
    float* r2    = (float*)alloc(2048 * 4);
    u16*   dh2b  = (u16*)alloc((size_t)2048 * 256 * 2);
    float* d_a1  = (float*)alloc((size_t)2048 * 1024 * 4);
    u16*   dh1b  = (u16*)alloc((size_t)2048 * 1024 * 2);
    u16*   de_bf = (u16*)alloc((size_t)2048 * 1024 * 2);
    float* Cpart = (float*)(ws + off);
    size_t cpartBytes = (ws_size > off) ? (ws_size - off) : 0;
    (void)in_sizes; (void)n_in; (void)out_size;

    const float sF = 1.0f / sqrtf(21504.0f);

    // split-K GEMM helper: N,M multiples of 128; ldC == N
    auto gemm = [&](const u16* A, int ldA, const u16* B, int ldB, int M, int N, int K,
                    int SKwant, float scale, const float* bias,
                    float* Cf, u16* Cb, int ldC) {
        int SK = SKwant;
        size_t slice = (size_t)M * ldC * 4;
        if (SK > 1 && cpartBytes < 2 * slice) SK = 1;
        if (SK > 1 && (size_t)SK * slice > cpartBytes) SK = (int)(cpartBytes / slice);
        while (SK > 1 && !((K % SK) == 0 && ((K / SK) % 32) == 0)) SK--;
        dim3 grid(N / 128, M / 128, SK);
        if (SK > 1) {
            k_gemm2<<<grid, 256, 0, stream>>>(A, ldA, B, ldB, K / SK, 0.f, nullptr,
                                              nullptr, nullptr, ldC, Cpart);
            int total = M * ldC;
            k_reduce<<<(total + 255) / 256, 256, 0, stream>>>(Cpart, (size_t)M * ldC, SK,
                                                              total, N, scale, bias, Cf, Cb);
        } else {
            k_gemm2<<<grid, 256, 0, stream>>>(A, ldA, B, ldB, K, scale, bias,
                                              Cf, Cb, ldC, nullptr);
        }
    };

    // weight prep (W^T layouts for forward GEMMs)
    k_transpose<<<dim3(32, 512), 256, 0, stream>>>(w0, 16384, 1024, Wtb, 21504, 0);
    k_transpose<<<dim3(32, 128), 256, 0, stream>>>(w1, 4096, 1024, Wtb, 21504, 16384);
    k_transpose<<<dim3(32, 32),  256, 0, stream>>>(w2, 1024, 1024, Wtb, 21504, 20480);
    k_transpose<<<dim3(32, 32),  256, 0, stream>>>(W1, 1024, 1024, W1tb, 1024, 0);
    k_transpose<<<dim3(8, 32),   256, 0, stream>>>(W2, 1024, 256, W2tb, 1024, 0);
    k_convert<<<1024 * 1024 / 1024, 256, 0, stream>>>(W1, W1b, 1024 * 1024 / 4);
    k_convert<<<1024 * 256 / 1024, 256, 0, stream>>>(W2, W2b, 1024 * 256 / 4);

    // features -> P
    k_features<<<2048, 256, 0, stream>>>(t, PG);

    // h = sF * P @ Wt^T  (bf16 out), split-K for occupancy
    gemm(PG, 21504, Wtb, 21504, 2048, 1024, 21504, 8, sF, nullptr, nullptr, h_bf, 1024);

    // Wtb dead -> overwrite with straight-layout Wb (for G = de @ W)
    u16* Wb = Wtb;
    k_convert<<<16384 * 1024 / 1024, 256, 0, stream>>>(w0, Wb, 16384 * 1024 / 4);
    k_convert<<<4096 * 1024 / 1024, 256, 0, stream>>>(w1, Wb + (size_t)16384 * 1024, 4096 * 1024 / 4);
    k_convert<<<1024 * 1024 / 1024, 256, 0, stream>>>(w2, Wb + (size_t)20480 * 1024, 1024 * 1024 / 4);

    // MLP forward
    gemm(h_bf, 1024, W1tb, 1024, 2048, 1024, 1024, 2, 1.0f, b1, h1pre, nullptr, 1024);
    k_ln_fwd<<<2048, 256, 0, stream>>>(h1pre, 1024, g1, be1, mu1, r1, a1_bf, nullptr);
    gemm(a1_bf, 1024, W2tb, 1024, 2048, 256, 1024, 8, 1.0f, b2, h2pre, nullptr, 256);
    k_ln_fwd<<<2048, 256, 0, stream>>>(h2pre, 256, g2, be2, mu2, r2, nullptr, xout);

    // backward
    k_ln_bwd<<<2048, 256, 0, stream>>>(nullptr, h2pre, mu2, r2, g2, be2, dh2b, 256);
    gemm(dh2b, 256, W2b, 256, 2048, 1024, 256, 2, 1.0f, nullptr, d_a1, nullptr, 1024);
    k_ln_bwd<<<2048, 256, 0, stream>>>(d_a1, h1pre, mu1, r1, g1, be1, dh1b, 1024);
    gemm(dh1b, 1024, W1b, 1024, 2048, 1024, 1024, 2, sF, nullptr, nullptr, de_bf, 1024);

    // G = de @ W (NT, straight Wb), bf16 out, aliases P — 168x16 = 2688 blocks
    gemm(de_bf, 1024, Wb, 1024, 2048, 21504, 1024, 1, 1.0f, nullptr, nullptr, PG, 21504);

    // y = (G+G^T) x per segment
    k_contract<<<2048, 512, 0, stream>>>(PG, t, yout);
}